// Round 1
// baseline (796.579 us; speedup 1.0000x reference)
//
#include <hip/hip_runtime.h>

// SDConv on MI355X.
// Identity used: spmm(L, X) @ W == spmm(L, X @ W)  (row-mix and col-mix commute).
// Phase 0: out = bias broadcast.
// Phase 1: XW[node][2k+c][64] = (c==0 ? X_real : X_imag) @ W[k]   (6 N x 64x64 GEMMs, fused)
// Phase 2: one pass over edges: per edge gather node `col`'s 6x64 block (contiguous 1536 B),
//          combine with 6 L scalars, atomicAdd 64 floats into real[row] and imag[row].

constexpr int N_NODES = 100000;
constexpr int E_EDGES = 1600000;
constexpr int CH = 64;

__global__ __launch_bounds__(256) void init_out_kernel(const float* __restrict__ bias,
                                                       float* __restrict__ out) {
    int i = blockIdx.x * 256 + threadIdx.x;   // grid sized exactly: 2*N*64 threads
    out[i] = bias[i & 63];
}

// Computes XW for NK spectral orders at once.
// W: [NK][64][64] row-major (in: j, out: col). XW: [N][2*NK][64].
template <int NK>
__global__ __launch_bounds__(256) void xw_kernel(const float* __restrict__ Xr,
                                                 const float* __restrict__ Xi,
                                                 const float* __restrict__ W,
                                                 float* __restrict__ XW) {
    __shared__ float sW[NK][64][64];     // [k][j][col]  (48 KB for NK=3)
    __shared__ float4 sX4[2][32][16];    // [c][row][j4] (16 KB)
    const int tid = threadIdx.x;

    // Stage W (NK*4096 floats) as float4, coalesced.
    float4* swf = (float4*)&sW[0][0][0];
    const float4* gW = (const float4*)W;
    for (int i = tid; i < NK * 1024; i += 256) swf[i] = gW[i];

    // Stage 32-row X tiles (exact: N % 32 == 0, grid = N/32).
    const int rowbase = blockIdx.x * 32;
    float4* sxf = (float4*)sX4;
    const float4* gXr = (const float4*)(Xr + (size_t)rowbase * CH);
    const float4* gXi = (const float4*)(Xi + (size_t)rowbase * CH);
    for (int i = tid; i < 512; i += 256) {
        sxf[i] = gXr[i];
        sxf[512 + i] = gXi[i];
    }
    __syncthreads();

    const int col = tid & 63;   // lane == col -> stride-1 LDS (conflict-free), coalesced stores
    const int rg = tid >> 6;    // wave id: rows rg*8 .. rg*8+7 (sX reads are wave-broadcast)

    float acc[8][2 * NK];
#pragma unroll
    for (int i = 0; i < 8; ++i)
#pragma unroll
        for (int c2 = 0; c2 < 2 * NK; ++c2) acc[i][c2] = 0.0f;

#pragma unroll 2
    for (int j4 = 0; j4 < 16; ++j4) {
        float w[NK][4];
#pragma unroll
        for (int k = 0; k < NK; ++k)
#pragma unroll
            for (int jj = 0; jj < 4; ++jj) w[k][jj] = sW[k][j4 * 4 + jj][col];
#pragma unroll
        for (int i = 0; i < 8; ++i) {
            float4 xr = sX4[0][rg * 8 + i][j4];   // ds_read_b128, same addr per wave
            float4 xi = sX4[1][rg * 8 + i][j4];
            const float xra[4] = {xr.x, xr.y, xr.z, xr.w};
            const float xia[4] = {xi.x, xi.y, xi.z, xi.w};
#pragma unroll
            for (int jj = 0; jj < 4; ++jj)
#pragma unroll
                for (int k = 0; k < NK; ++k) {
                    acc[i][2 * k] += xra[jj] * w[k][jj];
                    acc[i][2 * k + 1] += xia[jj] * w[k][jj];
                }
        }
    }

#pragma unroll
    for (int i = 0; i < 8; ++i) {
        size_t base = (size_t)(rowbase + rg * 8 + i) * (2 * NK * 64);
#pragma unroll
        for (int ck = 0; ck < 2 * NK; ++ck) XW[base + (size_t)ck * 64 + col] = acc[i][ck];
    }
}

// One wave (64 lanes) per edge; lane == channel.
template <int NK>
__global__ __launch_bounds__(256) void edge_kernel(const int* __restrict__ rows,
                                                   const int* __restrict__ cols,
                                                   const float* __restrict__ Lr,
                                                   const float* __restrict__ Li,
                                                   const float* __restrict__ XW,
                                                   float* __restrict__ out) {
    const int gid = blockIdx.x * 256 + threadIdx.x;
    const int e = gid >> 6;
    const int lane = gid & 63;
    if (e >= E_EDGES) return;

    const int row = rows[e];
    const int colN = cols[e];
    const float* p = XW + (size_t)colN * (2 * NK * 64);

    float rc = 0.0f, ic = 0.0f;
#pragma unroll
    for (int k = 0; k < NK; ++k) {
        const float lr = Lr[(size_t)k * E_EDGES + e];   // wave-uniform, L1 broadcast
        const float li = Li[(size_t)k * E_EDGES + e];
        const float xr = p[(2 * k) * 64 + lane];        // coalesced 256 B per wave
        const float xi = p[(2 * k + 1) * 64 + lane];
        rc += lr * xr - li * xi;
        ic += li * xr + lr * xi;
    }
    unsafeAtomicAdd(out + (size_t)row * 64 + lane, rc);                    // real part
    unsafeAtomicAdd(out + ((size_t)N_NODES + row) * 64 + lane, ic);        // imag part
}

extern "C" void kernel_launch(void* const* d_in, const int* in_sizes, int n_in,
                              void* d_out, int out_size, void* d_ws, size_t ws_size,
                              hipStream_t stream) {
    const float* Xr = (const float*)d_in[0];
    const float* Xi = (const float*)d_in[1];
    const int* ei = (const int*)d_in[2];
    const float* Lr = (const float*)d_in[3];
    const float* Li = (const float*)d_in[4];
    const float* W = (const float*)d_in[5];
    const float* bias = (const float*)d_in[6];
    float* out = (float*)d_out;
    float* XW = (float*)d_ws;

    const int* rows = ei;              // edge_index[0]
    const int* cols = ei + E_EDGES;    // edge_index[1]

    // Phase 0: out = bias (also makes each replay deterministic after poisoning).
    const int total = 2 * N_NODES * CH;                 // 12.8M, divisible by 256
    init_out_kernel<<<total / 256, 256, 0, stream>>>(bias, out);

    const size_t need_full = (size_t)N_NODES * (6 * CH) * sizeof(float);  // 153.6 MB
    const int gemm_grid = N_NODES / 32;                                   // 3125 exact
    const int edge_grid = (int)((size_t)E_EDGES * 64 / 256);              // 400000 exact

    if (ws_size >= need_full) {
        xw_kernel<3><<<gemm_grid, 256, 0, stream>>>(Xr, Xi, W, XW);
        edge_kernel<3><<<edge_grid, 256, 0, stream>>>(rows, cols, Lr, Li, XW, out);
    } else {
        // Fallback: per-order passes, needs only N*128*4 = 51.2 MB of ws.
        for (int k = 0; k < 3; ++k) {
            xw_kernel<1><<<gemm_grid, 256, 0, stream>>>(Xr, Xi, W + (size_t)k * 4096, XW);
            edge_kernel<1><<<edge_grid, 256, 0, stream>>>(rows, cols,
                                                          Lr + (size_t)k * E_EDGES,
                                                          Li + (size_t)k * E_EDGES, XW, out);
        }
    }
}

// Round 3
// 606.719 us; speedup vs baseline: 1.3129x; 1.3129x over previous
//
#include <hip/hip_runtime.h>

// SDConv on MI355X.
// Identity: spmm(L, X) @ W == spmm(L, X @ W).
// Main path (needs ~206 MB ws):
//   1. XW[node][k][ch][(re,im)] = (X_real|X_imag) @ W[k]   (fused 6 GEMMs)
//   2. Build CSR by row on device: histogram -> scan -> payload scatter (32 B/edge: col + 6 L).
//   3. row_kernel: one wave per row, lane=channel, register accumulate, plain stores (+bias).
// Fallback paths keep round-1 atomic-scatter structure.

constexpr int N_NODES = 100000;
constexpr int E_EDGES = 1600000;
constexpr int CH = 64;
constexpr int NP = 100096;          // N padded to multiple of 256 (391*256)
constexpr int NBLK = NP / 256;      // 391

typedef float f32x4 __attribute__((ext_vector_type(4)));

__global__ __launch_bounds__(256) void init_out_kernel(const float* __restrict__ bias,
                                                       float* __restrict__ out) {
    int i = blockIdx.x * 256 + threadIdx.x;   // grid sized exactly: 2*N*64 threads
    out[i] = bias[i & 63];
}

// ---------------- Phase 1: XW = X @ W, interleaved (re,im) float2 layout ----------------
// W: [NK][64][64] row-major. XW: [N][NK][64][2] floats (node stride NK*128).
template <int NK>
__global__ __launch_bounds__(256) void xw_kernel(const float* __restrict__ Xr,
                                                 const float* __restrict__ Xi,
                                                 const float* __restrict__ W,
                                                 float* __restrict__ XW) {
    __shared__ float sW[NK][64][64];     // [k][j][col]
    __shared__ float4 sX4[2][32][16];    // [c][row][j4]
    const int tid = threadIdx.x;

    float4* swf = (float4*)&sW[0][0][0];
    const float4* gW = (const float4*)W;
    for (int i = tid; i < NK * 1024; i += 256) swf[i] = gW[i];

    const int rowbase = blockIdx.x * 32;
    float4* sxf = (float4*)sX4;
    const float4* gXr = (const float4*)(Xr + (size_t)rowbase * CH);
    const float4* gXi = (const float4*)(Xi + (size_t)rowbase * CH);
    for (int i = tid; i < 512; i += 256) {
        sxf[i] = gXr[i];
        sxf[512 + i] = gXi[i];
    }
    __syncthreads();

    const int col = tid & 63;
    const int rg = tid >> 6;

    float acc[8][2 * NK];
#pragma unroll
    for (int i = 0; i < 8; ++i)
#pragma unroll
        for (int c2 = 0; c2 < 2 * NK; ++c2) acc[i][c2] = 0.0f;

#pragma unroll 2
    for (int j4 = 0; j4 < 16; ++j4) {
        float w[NK][4];
#pragma unroll
        for (int k = 0; k < NK; ++k)
#pragma unroll
            for (int jj = 0; jj < 4; ++jj) w[k][jj] = sW[k][j4 * 4 + jj][col];
#pragma unroll
        for (int i = 0; i < 8; ++i) {
            float4 xr = sX4[0][rg * 8 + i][j4];
            float4 xi = sX4[1][rg * 8 + i][j4];
            const float xra[4] = {xr.x, xr.y, xr.z, xr.w};
            const float xia[4] = {xi.x, xi.y, xi.z, xi.w};
#pragma unroll
            for (int jj = 0; jj < 4; ++jj)
#pragma unroll
                for (int k = 0; k < NK; ++k) {
                    acc[i][2 * k] += xra[jj] * w[k][jj];
                    acc[i][2 * k + 1] += xia[jj] * w[k][jj];
                }
        }
    }

#pragma unroll
    for (int i = 0; i < 8; ++i) {
        float2* dst = (float2*)(XW + (size_t)(rowbase + rg * 8 + i) * (NK * 128));
#pragma unroll
        for (int k = 0; k < NK; ++k) {
            float2 v;
            v.x = acc[i][2 * k];
            v.y = acc[i][2 * k + 1];
            dst[k * 64 + col] = v;    // lane==col -> coalesced 512 B store
        }
    }
}

// ---------------- CSR build ----------------
__global__ __launch_bounds__(256) void zero_counts_kernel(int* __restrict__ counts) {
    counts[blockIdx.x * 256 + threadIdx.x] = 0;   // grid = NBLK
}

__global__ __launch_bounds__(256) void hist_kernel(const int* __restrict__ rows,
                                                   int* __restrict__ counts) {
    int e = blockIdx.x * 256 + threadIdx.x;       // grid = E/256 exact
    if (e < E_EDGES) atomicAdd(&counts[rows[e]], 1);
}

__global__ __launch_bounds__(256) void scan_a_kernel(const int* __restrict__ counts,
                                                     int* __restrict__ rowst,
                                                     int* __restrict__ btot) {
    __shared__ int s[256];
    const int t = threadIdx.x;
    const int g = blockIdx.x * 256 + t;
    int v = counts[g];
    s[t] = v;
    __syncthreads();
    for (int off = 1; off < 256; off <<= 1) {
        int a = (t >= off) ? s[t - off] : 0;
        __syncthreads();
        s[t] += a;
        __syncthreads();
    }
    rowst[g] = s[t] - v;                 // block-local exclusive prefix
    if (t == 255) btot[blockIdx.x] = s[255];
}

__global__ __launch_bounds__(512) void scan_b_kernel(int* __restrict__ btot) {
    __shared__ int s[512];
    const int t = threadIdx.x;
    int v = (t < NBLK) ? btot[t] : 0;
    s[t] = v;
    __syncthreads();
    for (int off = 1; off < 512; off <<= 1) {
        int a = (t >= off) ? s[t - off] : 0;
        __syncthreads();
        s[t] += a;
        __syncthreads();
    }
    if (t < NBLK) btot[t] = s[t] - v;    // exclusive, in place
}

__global__ __launch_bounds__(256) void scan_c_kernel(const int* __restrict__ btot,
                                                     int* __restrict__ rowst,
                                                     int* __restrict__ cursor) {
    const int g = blockIdx.x * 256 + threadIdx.x;
    int v = rowst[g] + btot[blockIdx.x];
    rowst[g] = v;
    cursor[g] = v;
}

// payload per edge: 2x float4 = {col, pad, lr0, li0}, {lr1, li1, lr2, li2}
__global__ __launch_bounds__(256) void scatter_kernel(const int* __restrict__ rows,
                                                      const int* __restrict__ cols,
                                                      const float* __restrict__ Lr,
                                                      const float* __restrict__ Li,
                                                      int* __restrict__ cursor,
                                                      float4* __restrict__ payload) {
    int e = blockIdx.x * 256 + threadIdx.x;
    if (e >= E_EDGES) return;
    int r = rows[e];
    int pos = atomicAdd(&cursor[r], 1);
    float4 p0, p1;
    p0.x = __int_as_float(cols[e]);
    p0.y = 0.0f;
    p0.z = Lr[e];
    p0.w = Li[e];
    p1.x = Lr[E_EDGES + e];
    p1.y = Li[E_EDGES + e];
    p1.z = Lr[2 * E_EDGES + e];
    p1.w = Li[2 * E_EDGES + e];
    payload[(size_t)pos * 2] = p0;
    payload[(size_t)pos * 2 + 1] = p1;
}

// ---------------- Main pass: one wave per row, no atomics ----------------
__global__ __launch_bounds__(256) void row_kernel(const int* __restrict__ rowst,
                                                  const float* __restrict__ payload,
                                                  const float* __restrict__ XW,
                                                  const float* __restrict__ bias,
                                                  float* __restrict__ out) {
    const int r = blockIdx.x * 4 + (threadIdx.x >> 6);
    const int lane = threadIdx.x & 63;
    if (r >= N_NODES) return;
    const int start = rowst[r];
    const int end = rowst[r + 1];
    const float b = bias[lane];
    float accR = 0.0f, accI = 0.0f;
#pragma unroll 2
    for (int p = start; p < end; ++p) {
        f32x4 q0 = __builtin_nontemporal_load((const f32x4*)(payload + (size_t)p * 8));
        f32x4 q1 = __builtin_nontemporal_load((const f32x4*)(payload + (size_t)p * 8 + 4));
        const int col = __float_as_int(q0.x);
        const float2* xw = (const float2*)(XW + (size_t)col * 384);
        float2 v0 = xw[lane];            // k=0, coalesced 512 B
        float2 v1 = xw[64 + lane];       // k=1
        float2 v2 = xw[128 + lane];      // k=2
        accR += q0.z * v0.x - q0.w * v0.y;
        accI += q0.w * v0.x + q0.z * v0.y;
        accR += q1.x * v1.x - q1.y * v1.y;
        accI += q1.y * v1.x + q1.x * v1.y;
        accR += q1.z * v2.x - q1.w * v2.y;
        accI += q1.w * v2.x + q1.z * v2.y;
    }
    __builtin_nontemporal_store(accR + b, &out[(size_t)r * 64 + lane]);
    __builtin_nontemporal_store(accI + b, &out[(size_t)(N_NODES + r) * 64 + lane]);
}

// ---------------- Fallback: atomic edge scatter (round-1 structure, float2 layout) ----------------
template <int NK>
__global__ __launch_bounds__(256) void edge_kernel(const int* __restrict__ rows,
                                                   const int* __restrict__ cols,
                                                   const float* __restrict__ Lr,
                                                   const float* __restrict__ Li,
                                                   const float* __restrict__ XW,
                                                   float* __restrict__ out) {
    const int gid = blockIdx.x * 256 + threadIdx.x;
    const int e = gid >> 6;
    const int lane = gid & 63;
    if (e >= E_EDGES) return;

    const int row = rows[e];
    const int colN = cols[e];
    const float2* xw = (const float2*)(XW + (size_t)colN * (NK * 128));

    float rc = 0.0f, ic = 0.0f;
#pragma unroll
    for (int k = 0; k < NK; ++k) {
        const float lr = Lr[(size_t)k * E_EDGES + e];
        const float li = Li[(size_t)k * E_EDGES + e];
        float2 v = xw[k * 64 + lane];
        rc += lr * v.x - li * v.y;
        ic += li * v.x + lr * v.y;
    }
    unsafeAtomicAdd(out + (size_t)row * 64 + lane, rc);
    unsafeAtomicAdd(out + ((size_t)N_NODES + row) * 64 + lane, ic);
}

extern "C" void kernel_launch(void* const* d_in, const int* in_sizes, int n_in,
                              void* d_out, int out_size, void* d_ws, size_t ws_size,
                              hipStream_t stream) {
    const float* Xr = (const float*)d_in[0];
    const float* Xi = (const float*)d_in[1];
    const int* ei = (const int*)d_in[2];
    const float* Lr = (const float*)d_in[3];
    const float* Li = (const float*)d_in[4];
    const float* W = (const float*)d_in[5];
    const float* bias = (const float*)d_in[6];
    float* out = (float*)d_out;

    const int* rows = ei;
    const int* cols = ei + E_EDGES;

    // ws layout
    char* wsb = (char*)d_ws;
    float* XW = (float*)wsb;                                      // 153,600,000 B
    float* payload = (float*)(wsb + 153600000);                   //  51,200,000 B
    int* counts = (int*)(wsb + 204800000);                        //     400,384 B
    int* rowst = (int*)(wsb + 205200384);                         //     400,384 B
    int* cursor = (int*)(wsb + 205600768);                        //     400,384 B
    int* btot = (int*)(wsb + 206001152);                          //       2,048 B
    const size_t need_full = 206003200;
    const size_t need_onepass = 153600000;

    const int gemm_grid = N_NODES / 32;                           // 3125
    const int edge_grid = (int)((size_t)E_EDGES * 64 / 256);      // 400000
    const int e_grid = E_EDGES / 256;                             // 6250

    if (ws_size >= need_full) {
        // CSR build
        zero_counts_kernel<<<NBLK, 256, 0, stream>>>(counts);
        hist_kernel<<<e_grid, 256, 0, stream>>>(rows, counts);
        scan_a_kernel<<<NBLK, 256, 0, stream>>>(counts, rowst, btot);
        scan_b_kernel<<<1, 512, 0, stream>>>(btot);
        scan_c_kernel<<<NBLK, 256, 0, stream>>>(btot, rowst, cursor);
        scatter_kernel<<<e_grid, 256, 0, stream>>>(rows, cols, Lr, Li, cursor,
                                                   (float4*)payload);
        // XW GEMMs
        xw_kernel<3><<<gemm_grid, 256, 0, stream>>>(Xr, Xi, W, XW);
        // main pass
        row_kernel<<<(N_NODES + 3) / 4, 256, 0, stream>>>(rowst, payload, XW, bias, out);
    } else if (ws_size >= need_onepass) {
        init_out_kernel<<<2 * N_NODES * CH / 256, 256, 0, stream>>>(bias, out);
        xw_kernel<3><<<gemm_grid, 256, 0, stream>>>(Xr, Xi, W, XW);
        edge_kernel<3><<<edge_grid, 256, 0, stream>>>(rows, cols, Lr, Li, XW, out);
    } else {
        init_out_kernel<<<2 * N_NODES * CH / 256, 256, 0, stream>>>(bias, out);
        for (int k = 0; k < 3; ++k) {
            xw_kernel<1><<<gemm_grid, 256, 0, stream>>>(Xr, Xi, W + (size_t)k * 4096, XW);
            edge_kernel<1><<<edge_grid, 256, 0, stream>>>(rows, cols,
                                                          Lr + (size_t)k * E_EDGES,
                                                          Li + (size_t)k * E_EDGES, XW, out);
        }
    }
}

// Round 4
// 450.805 us; speedup vs baseline: 1.7670x; 1.3459x over previous
//
#include <hip/hip_runtime.h>
#include <hip/hip_fp16.h>

// SDConv on MI355X.
// Identity: spmm(L, X) @ W == spmm(L, X @ W).
// Main path:
//   1. XWh[node][k][ch] = half2(re,im) of (X @ W[k])   (fused 6 GEMMs, fp16 storage: 76.8 MB
//      so the whole gather working set is L3-resident; fp32 accumulate everywhere)
//   2. Build CSR by row on device: histogram -> scan -> payload scatter (32 B/edge).
//   3. row_kernel: one wave per row, lane=channel, register accumulate, plain stores (+bias).

constexpr int N_NODES = 100000;
constexpr int E_EDGES = 1600000;
constexpr int CH = 64;
constexpr int NP = 100096;          // N padded to multiple of 256 (391*256)
constexpr int NBLK = NP / 256;      // 391

typedef float f32x4 __attribute__((ext_vector_type(4)));

__global__ __launch_bounds__(256) void init_out_kernel(const float* __restrict__ bias,
                                                       float* __restrict__ out) {
    int i = blockIdx.x * 256 + threadIdx.x;
    out[i] = bias[i & 63];
}

// ---------------- Phase 1: XWh = X @ W, half2(re,im) layout ----------------
// W: [NK][64][64] row-major. XWh: [N][NK][64] half2 (node stride NK*64 half2).
template <int NK>
__global__ __launch_bounds__(256) void xw_kernel(const float* __restrict__ Xr,
                                                 const float* __restrict__ Xi,
                                                 const float* __restrict__ W,
                                                 __half2* __restrict__ XWh) {
    __shared__ float sW[NK][64][64];     // [k][j][col]
    __shared__ float4 sX4[2][32][16];    // [c][row][j4]
    const int tid = threadIdx.x;

    float4* swf = (float4*)&sW[0][0][0];
    const float4* gW = (const float4*)W;
    for (int i = tid; i < NK * 1024; i += 256) swf[i] = gW[i];

    const int rowbase = blockIdx.x * 32;
    float4* sxf = (float4*)sX4;
    const float4* gXr = (const float4*)(Xr + (size_t)rowbase * CH);
    const float4* gXi = (const float4*)(Xi + (size_t)rowbase * CH);
    for (int i = tid; i < 512; i += 256) {
        sxf[i] = gXr[i];
        sxf[512 + i] = gXi[i];
    }
    __syncthreads();

    const int col = tid & 63;
    const int rg = tid >> 6;

    float acc[8][2 * NK];
#pragma unroll
    for (int i = 0; i < 8; ++i)
#pragma unroll
        for (int c2 = 0; c2 < 2 * NK; ++c2) acc[i][c2] = 0.0f;

#pragma unroll 2
    for (int j4 = 0; j4 < 16; ++j4) {
        float w[NK][4];
#pragma unroll
        for (int k = 0; k < NK; ++k)
#pragma unroll
            for (int jj = 0; jj < 4; ++jj) w[k][jj] = sW[k][j4 * 4 + jj][col];
#pragma unroll
        for (int i = 0; i < 8; ++i) {
            float4 xr = sX4[0][rg * 8 + i][j4];
            float4 xi = sX4[1][rg * 8 + i][j4];
            const float xra[4] = {xr.x, xr.y, xr.z, xr.w};
            const float xia[4] = {xi.x, xi.y, xi.z, xi.w};
#pragma unroll
            for (int jj = 0; jj < 4; ++jj)
#pragma unroll
                for (int k = 0; k < NK; ++k) {
                    acc[i][2 * k] += xra[jj] * w[k][jj];
                    acc[i][2 * k + 1] += xia[jj] * w[k][jj];
                }
        }
    }

#pragma unroll
    for (int i = 0; i < 8; ++i) {
        __half2* dst = XWh + (size_t)(rowbase + rg * 8 + i) * (NK * 64);
#pragma unroll
        for (int k = 0; k < NK; ++k)
            dst[k * 64 + col] = __floats2half2_rn(acc[i][2 * k], acc[i][2 * k + 1]);
    }
}

// ---------------- CSR build ----------------
__global__ __launch_bounds__(256) void zero_counts_kernel(int* __restrict__ counts) {
    counts[blockIdx.x * 256 + threadIdx.x] = 0;   // grid = NBLK
}

__global__ __launch_bounds__(256) void hist_kernel(const int* __restrict__ rows,
                                                   int* __restrict__ counts) {
    int e = blockIdx.x * 256 + threadIdx.x;       // grid = E/256 exact
    if (e < E_EDGES) atomicAdd(&counts[rows[e]], 1);
}

__global__ __launch_bounds__(256) void scan_a_kernel(const int* __restrict__ counts,
                                                     int* __restrict__ rowst,
                                                     int* __restrict__ btot) {
    __shared__ int s[256];
    const int t = threadIdx.x;
    const int g = blockIdx.x * 256 + t;
    int v = counts[g];
    s[t] = v;
    __syncthreads();
    for (int off = 1; off < 256; off <<= 1) {
        int a = (t >= off) ? s[t - off] : 0;
        __syncthreads();
        s[t] += a;
        __syncthreads();
    }
    rowst[g] = s[t] - v;
    if (t == 255) btot[blockIdx.x] = s[255];
}

__global__ __launch_bounds__(512) void scan_b_kernel(int* __restrict__ btot) {
    __shared__ int s[512];
    const int t = threadIdx.x;
    int v = (t < NBLK) ? btot[t] : 0;
    s[t] = v;
    __syncthreads();
    for (int off = 1; off < 512; off <<= 1) {
        int a = (t >= off) ? s[t - off] : 0;
        __syncthreads();
        s[t] += a;
        __syncthreads();
    }
    if (t < NBLK) btot[t] = s[t] - v;
}

__global__ __launch_bounds__(256) void scan_c_kernel(const int* __restrict__ btot,
                                                     int* __restrict__ rowst,
                                                     int* __restrict__ cursor) {
    const int g = blockIdx.x * 256 + threadIdx.x;
    int v = rowst[g] + btot[blockIdx.x];
    rowst[g] = v;
    cursor[g] = v;
}

// payload per edge: 2x float4 = {col, pad, lr0, li0}, {lr1, li1, lr2, li2}
__global__ __launch_bounds__(256) void scatter_kernel(const int* __restrict__ rows,
                                                      const int* __restrict__ cols,
                                                      const float* __restrict__ Lr,
                                                      const float* __restrict__ Li,
                                                      int* __restrict__ cursor,
                                                      float4* __restrict__ payload) {
    int e = blockIdx.x * 256 + threadIdx.x;
    if (e >= E_EDGES) return;
    int r = rows[e];
    int pos = atomicAdd(&cursor[r], 1);
    float4 p0, p1;
    p0.x = __int_as_float(cols[e]);
    p0.y = 0.0f;
    p0.z = Lr[e];
    p0.w = Li[e];
    p1.x = Lr[E_EDGES + e];
    p1.y = Li[E_EDGES + e];
    p1.z = Lr[2 * E_EDGES + e];
    p1.w = Li[2 * E_EDGES + e];
    payload[(size_t)pos * 2] = p0;
    payload[(size_t)pos * 2 + 1] = p1;
}

// ---------------- Main pass: one wave per row, no atomics, fp16 gather ----------------
__global__ __launch_bounds__(256) void row_kernel(const int* __restrict__ rowst,
                                                  const float* __restrict__ payload,
                                                  const __half2* __restrict__ XWh,
                                                  const float* __restrict__ bias,
                                                  float* __restrict__ out) {
    const int r = blockIdx.x * 4 + (threadIdx.x >> 6);
    const int lane = threadIdx.x & 63;
    if (r >= N_NODES) return;
    const int start = rowst[r];
    const int end = rowst[r + 1];
    const float b = bias[lane];
    float accR = 0.0f, accI = 0.0f;
#pragma unroll 2
    for (int p = start; p < end; ++p) {
        f32x4 q0 = __builtin_nontemporal_load((const f32x4*)(payload + (size_t)p * 8));
        f32x4 q1 = __builtin_nontemporal_load((const f32x4*)(payload + (size_t)p * 8 + 4));
        const int col = __float_as_int(q0.x);
        const __half2* xw = XWh + (size_t)col * 192;
        float2 v0 = __half22float2(xw[lane]);          // k=0, coalesced 256 B
        float2 v1 = __half22float2(xw[64 + lane]);     // k=1
        float2 v2 = __half22float2(xw[128 + lane]);    // k=2
        accR += q0.z * v0.x - q0.w * v0.y;
        accI += q0.w * v0.x + q0.z * v0.y;
        accR += q1.x * v1.x - q1.y * v1.y;
        accI += q1.y * v1.x + q1.x * v1.y;
        accR += q1.z * v2.x - q1.w * v2.y;
        accI += q1.w * v2.x + q1.z * v2.y;
    }
    __builtin_nontemporal_store(accR + b, &out[(size_t)r * 64 + lane]);
    __builtin_nontemporal_store(accI + b, &out[(size_t)(N_NODES + r) * 64 + lane]);
}

// ---------------- Fallback: atomic edge scatter (fp16 XW) ----------------
template <int NK>
__global__ __launch_bounds__(256) void edge_kernel(const int* __restrict__ rows,
                                                   const int* __restrict__ cols,
                                                   const float* __restrict__ Lr,
                                                   const float* __restrict__ Li,
                                                   const __half2* __restrict__ XWh,
                                                   float* __restrict__ out) {
    const int gid = blockIdx.x * 256 + threadIdx.x;
    const int e = gid >> 6;
    const int lane = gid & 63;
    if (e >= E_EDGES) return;

    const int row = rows[e];
    const int colN = cols[e];
    const __half2* xw = XWh + (size_t)colN * (NK * 64);

    float rc = 0.0f, ic = 0.0f;
#pragma unroll
    for (int k = 0; k < NK; ++k) {
        const float lr = Lr[(size_t)k * E_EDGES + e];
        const float li = Li[(size_t)k * E_EDGES + e];
        float2 v = __half22float2(xw[k * 64 + lane]);
        rc += lr * v.x - li * v.y;
        ic += li * v.x + lr * v.y;
    }
    unsafeAtomicAdd(out + (size_t)row * 64 + lane, rc);
    unsafeAtomicAdd(out + ((size_t)N_NODES + row) * 64 + lane, ic);
}

extern "C" void kernel_launch(void* const* d_in, const int* in_sizes, int n_in,
                              void* d_out, int out_size, void* d_ws, size_t ws_size,
                              hipStream_t stream) {
    const float* Xr = (const float*)d_in[0];
    const float* Xi = (const float*)d_in[1];
    const int* ei = (const int*)d_in[2];
    const float* Lr = (const float*)d_in[3];
    const float* Li = (const float*)d_in[4];
    const float* W = (const float*)d_in[5];
    const float* bias = (const float*)d_in[6];
    float* out = (float*)d_out;

    const int* rows = ei;
    const int* cols = ei + E_EDGES;

    // ws layout (fp16 XW: 100000*192*4 B = 76,800,000)
    char* wsb = (char*)d_ws;
    __half2* XWh = (__half2*)wsb;                                 //  76,800,000 B
    float* payload = (float*)(wsb + 76800000);                    //  51,200,000 B
    int* counts = (int*)(wsb + 128000000);                        //     400,384 B
    int* rowst = (int*)(wsb + 128400384);                         //     400,384 B
    int* cursor = (int*)(wsb + 128800768);                        //     400,384 B
    int* btot = (int*)(wsb + 129201152);                          //       2,048 B
    const size_t need_full = 129203200;
    const size_t need_onepass = 76800000;

    const int gemm_grid = N_NODES / 32;                           // 3125
    const int edge_grid = (int)((size_t)E_EDGES * 64 / 256);      // 400000
    const int e_grid = E_EDGES / 256;                             // 6250

    if (ws_size >= need_full) {
        zero_counts_kernel<<<NBLK, 256, 0, stream>>>(counts);
        hist_kernel<<<e_grid, 256, 0, stream>>>(rows, counts);
        scan_a_kernel<<<NBLK, 256, 0, stream>>>(counts, rowst, btot);
        scan_b_kernel<<<1, 512, 0, stream>>>(btot);
        scan_c_kernel<<<NBLK, 256, 0, stream>>>(btot, rowst, cursor);
        scatter_kernel<<<e_grid, 256, 0, stream>>>(rows, cols, Lr, Li, cursor,
                                                   (float4*)payload);
        xw_kernel<3><<<gemm_grid, 256, 0, stream>>>(Xr, Xi, W, XWh);
        row_kernel<<<(N_NODES + 3) / 4, 256, 0, stream>>>(rowst, payload, XWh, bias, out);
    } else if (ws_size >= need_onepass) {
        init_out_kernel<<<2 * N_NODES * CH / 256, 256, 0, stream>>>(bias, out);
        xw_kernel<3><<<gemm_grid, 256, 0, stream>>>(Xr, Xi, W, XWh);
        edge_kernel<3><<<edge_grid, 256, 0, stream>>>(rows, cols, Lr, Li, XWh, out);
    } else {
        init_out_kernel<<<2 * N_NODES * CH / 256, 256, 0, stream>>>(bias, out);
        for (int k = 0; k < 3; ++k) {
            xw_kernel<1><<<gemm_grid, 256, 0, stream>>>(Xr, Xi, W + (size_t)k * 4096, XWh);
            edge_kernel<1><<<edge_grid, 256, 0, stream>>>(rows, cols,
                                                          Lr + (size_t)k * E_EDGES,
                                                          Li + (size_t)k * E_EDGES, XWh, out);
        }
    }
}

// Round 5
// 439.257 us; speedup vs baseline: 1.8135x; 1.0263x over previous
//
#include <hip/hip_runtime.h>
#include <hip/hip_fp16.h>

// SDConv on MI355X.
// Reference: out = sum_k spmm(L_k, X) @ W_k + bias  (complex).
// Round-5 structure: apply W AFTER the spmm (k-expansion is in the L domain, so the
// gather table is just X: 25.6 MB fp16 -> L3-resident).
//   1. xh_kernel:  Xh[node][ch] = half2(Xr, Xi)                      (25.6 MB)
//   2. CSR build:  histogram -> scan -> payload scatter (32 B/edge, fp32 L).
//   3. row_kernel: one wave per row; per edge gather 1 half2/lane; 6 fp32 acc/lane;
//                  write Y[node][k][ch] = half2(accR_k, accI_k)      (76.8 MB)
//   4. yw_kernel:  out = sum_k Y_k @ W_k + bias   (streaming VALU GEMM, fp32 acc)
// Fallback paths = round-4 proven structure.

constexpr int N_NODES = 100000;
constexpr int E_EDGES = 1600000;
constexpr int CH = 64;
constexpr int NP = 100096;          // N padded to multiple of 256
constexpr int NBLK = NP / 256;      // 391

typedef float f32x4 __attribute__((ext_vector_type(4)));

__global__ __launch_bounds__(256) void init_out_kernel(const float* __restrict__ bias,
                                                       float* __restrict__ out) {
    int i = blockIdx.x * 256 + threadIdx.x;
    out[i] = bias[i & 63];
}

// ---------------- Phase 1: Xh = half2(Xr, Xi), [N][64] ----------------
__global__ __launch_bounds__(256) void xh_kernel(const float* __restrict__ Xr,
                                                 const float* __restrict__ Xi,
                                                 __half2* __restrict__ Xh) {
    int i = blockIdx.x * 256 + threadIdx.x;   // grid = N*64/4/256 = 6250 exact
    const float4 r = ((const float4*)Xr)[i];
    const float4 m = ((const float4*)Xi)[i];
    __half2 h0 = __floats2half2_rn(r.x, m.x);
    __half2 h1 = __floats2half2_rn(r.y, m.y);
    __half2 h2 = __floats2half2_rn(r.z, m.z);
    __half2 h3 = __floats2half2_rn(r.w, m.w);
    uint4 u;
    u.x = __builtin_bit_cast(unsigned, h0);
    u.y = __builtin_bit_cast(unsigned, h1);
    u.z = __builtin_bit_cast(unsigned, h2);
    u.w = __builtin_bit_cast(unsigned, h3);
    ((uint4*)Xh)[i] = u;
}

// ---------------- CSR build ----------------
__global__ __launch_bounds__(256) void zero_counts_kernel(int* __restrict__ counts) {
    counts[blockIdx.x * 256 + threadIdx.x] = 0;   // grid = NBLK
}

__global__ __launch_bounds__(256) void hist_kernel(const int* __restrict__ rows,
                                                   int* __restrict__ counts) {
    int e = blockIdx.x * 256 + threadIdx.x;
    if (e < E_EDGES) atomicAdd(&counts[rows[e]], 1);
}

__global__ __launch_bounds__(256) void scan_a_kernel(const int* __restrict__ counts,
                                                     int* __restrict__ rowst,
                                                     int* __restrict__ btot) {
    __shared__ int s[256];
    const int t = threadIdx.x;
    const int g = blockIdx.x * 256 + t;
    int v = counts[g];
    s[t] = v;
    __syncthreads();
    for (int off = 1; off < 256; off <<= 1) {
        int a = (t >= off) ? s[t - off] : 0;
        __syncthreads();
        s[t] += a;
        __syncthreads();
    }
    rowst[g] = s[t] - v;
    if (t == 255) btot[blockIdx.x] = s[255];
}

__global__ __launch_bounds__(512) void scan_b_kernel(int* __restrict__ btot) {
    __shared__ int s[512];
    const int t = threadIdx.x;
    int v = (t < NBLK) ? btot[t] : 0;
    s[t] = v;
    __syncthreads();
    for (int off = 1; off < 512; off <<= 1) {
        int a = (t >= off) ? s[t - off] : 0;
        __syncthreads();
        s[t] += a;
        __syncthreads();
    }
    if (t < NBLK) btot[t] = s[t] - v;
}

__global__ __launch_bounds__(256) void scan_c_kernel(const int* __restrict__ btot,
                                                     int* __restrict__ rowst,
                                                     int* __restrict__ cursor) {
    const int g = blockIdx.x * 256 + threadIdx.x;
    int v = rowst[g] + btot[blockIdx.x];
    rowst[g] = v;
    cursor[g] = v;
}

// payload per edge: 2x float4 = {col, pad, lr0, li0}, {lr1, li1, lr2, li2}
__global__ __launch_bounds__(256) void scatter_kernel(const int* __restrict__ rows,
                                                      const int* __restrict__ cols,
                                                      const float* __restrict__ Lr,
                                                      const float* __restrict__ Li,
                                                      int* __restrict__ cursor,
                                                      float4* __restrict__ payload) {
    int e = blockIdx.x * 256 + threadIdx.x;
    if (e >= E_EDGES) return;
    int r = rows[e];
    int pos = atomicAdd(&cursor[r], 1);
    float4 p0, p1;
    p0.x = __int_as_float(cols[e]);
    p0.y = 0.0f;
    p0.z = Lr[e];
    p0.w = Li[e];
    p1.x = Lr[E_EDGES + e];
    p1.y = Li[E_EDGES + e];
    p1.z = Lr[2 * E_EDGES + e];
    p1.w = Li[2 * E_EDGES + e];
    payload[(size_t)pos * 2] = p0;
    payload[(size_t)pos * 2 + 1] = p1;
}

// ---------------- Main pass: one wave per row, gather X only ----------------
__global__ __launch_bounds__(256) void row2_kernel(const int* __restrict__ rowst,
                                                   const float* __restrict__ payload,
                                                   const __half2* __restrict__ Xh,
                                                   __half2* __restrict__ Y) {
    const int r = blockIdx.x * 4 + (threadIdx.x >> 6);
    const int lane = threadIdx.x & 63;
    if (r >= N_NODES) return;
    const int start = rowst[r];
    const int end = rowst[r + 1];
    float aR0 = 0.f, aI0 = 0.f, aR1 = 0.f, aI1 = 0.f, aR2 = 0.f, aI2 = 0.f;
#pragma unroll 2
    for (int p = start; p < end; ++p) {
        f32x4 q0 = __builtin_nontemporal_load((const f32x4*)(payload + (size_t)p * 8));
        f32x4 q1 = __builtin_nontemporal_load((const f32x4*)(payload + (size_t)p * 8 + 4));
        const int col = __float_as_int(q0.x);
        float2 x = __half22float2(Xh[(size_t)col * 64 + lane]);   // 1 dword gather/lane
        aR0 += q0.z * x.x - q0.w * x.y;
        aI0 += q0.w * x.x + q0.z * x.y;
        aR1 += q1.x * x.x - q1.y * x.y;
        aI1 += q1.y * x.x + q1.x * x.y;
        aR2 += q1.z * x.x - q1.w * x.y;
        aI2 += q1.w * x.x + q1.z * x.y;
    }
    __half2* yp = Y + (size_t)r * 192;
    yp[lane] = __floats2half2_rn(aR0, aI0);          // k=0
    yp[64 + lane] = __floats2half2_rn(aR1, aI1);     // k=1
    yp[128 + lane] = __floats2half2_rn(aR2, aI2);    // k=2
}

// ---------------- Phase 4: out = sum_k Y_k @ W_k + bias ----------------
// Y: [N][3][64] half2(re,im). W: [3][64][64] fp32. 32-row tiles, 8 rows/wave.
__global__ __launch_bounds__(256) void yw_kernel(const __half2* __restrict__ Y,
                                                 const float* __restrict__ W,
                                                 const float* __restrict__ bias,
                                                 float* __restrict__ out) {
    __shared__ float sW[3][64][64];      // 48 KB
    __shared__ __half2 sY[32][3][64];    // 24 KB
    const int tid = threadIdx.x;

    float4* swf = (float4*)&sW[0][0][0];
    const float4* gW = (const float4*)W;
    for (int i = tid; i < 3 * 1024; i += 256) swf[i] = gW[i];

    const int rowbase = blockIdx.x * 32;                 // grid = N/32 = 3125 exact
    float4* syf = (float4*)&sY[0][0][0];
    const float4* gY = (const float4*)(Y + (size_t)rowbase * 192);
    for (int i = tid; i < 1536; i += 256) syf[i] = gY[i];
    __syncthreads();

    const int col = tid & 63;
    const int rg = tid >> 6;
    const float b = bias[col];

    float accR[8], accI[8];
#pragma unroll
    for (int i = 0; i < 8; ++i) { accR[i] = 0.f; accI[i] = 0.f; }

#pragma unroll
    for (int k = 0; k < 3; ++k) {
#pragma unroll
        for (int j8 = 0; j8 < 8; ++j8) {
            float w[8];
#pragma unroll
            for (int jj = 0; jj < 8; ++jj) w[jj] = sW[k][j8 * 8 + jj][col];  // conflict-free
#pragma unroll
            for (int i = 0; i < 8; ++i) {
                const f32x4* yv = (const f32x4*)&sY[rg * 8 + i][k][j8 * 8];
#pragma unroll
                for (int h = 0; h < 2; ++h) {
                    f32x4 y4 = yv[h];
                    float ys[4] = {y4.x, y4.y, y4.z, y4.w};
#pragma unroll
                    for (int q = 0; q < 4; ++q) {
                        float2 v = __half22float2(__builtin_bit_cast(__half2, ys[q]));
                        accR[i] += v.x * w[h * 4 + q];
                        accI[i] += v.y * w[h * 4 + q];
                    }
                }
            }
        }
    }

#pragma unroll
    for (int i = 0; i < 8; ++i) {
        const int row = rowbase + rg * 8 + i;
        __builtin_nontemporal_store(accR[i] + b, &out[(size_t)row * 64 + col]);
        __builtin_nontemporal_store(accI[i] + b, &out[(size_t)(N_NODES + row) * 64 + col]);
    }
}

// ================= Round-4 fallback path (proven) =================
template <int NK>
__global__ __launch_bounds__(256) void xw_kernel(const float* __restrict__ Xr,
                                                 const float* __restrict__ Xi,
                                                 const float* __restrict__ W,
                                                 __half2* __restrict__ XWh) {
    __shared__ float sW[NK][64][64];
    __shared__ float4 sX4[2][32][16];
    const int tid = threadIdx.x;

    float4* swf = (float4*)&sW[0][0][0];
    const float4* gW = (const float4*)W;
    for (int i = tid; i < NK * 1024; i += 256) swf[i] = gW[i];

    const int rowbase = blockIdx.x * 32;
    float4* sxf = (float4*)sX4;
    const float4* gXr = (const float4*)(Xr + (size_t)rowbase * CH);
    const float4* gXi = (const float4*)(Xi + (size_t)rowbase * CH);
    for (int i = tid; i < 512; i += 256) {
        sxf[i] = gXr[i];
        sxf[512 + i] = gXi[i];
    }
    __syncthreads();

    const int col = tid & 63;
    const int rg = tid >> 6;

    float acc[8][2 * NK];
#pragma unroll
    for (int i = 0; i < 8; ++i)
#pragma unroll
        for (int c2 = 0; c2 < 2 * NK; ++c2) acc[i][c2] = 0.0f;

#pragma unroll 2
    for (int j4 = 0; j4 < 16; ++j4) {
        float w[NK][4];
#pragma unroll
        for (int k = 0; k < NK; ++k)
#pragma unroll
            for (int jj = 0; jj < 4; ++jj) w[k][jj] = sW[k][j4 * 4 + jj][col];
#pragma unroll
        for (int i = 0; i < 8; ++i) {
            float4 xr = sX4[0][rg * 8 + i][j4];
            float4 xi = sX4[1][rg * 8 + i][j4];
            const float xra[4] = {xr.x, xr.y, xr.z, xr.w};
            const float xia[4] = {xi.x, xi.y, xi.z, xi.w};
#pragma unroll
            for (int jj = 0; jj < 4; ++jj)
#pragma unroll
                for (int k = 0; k < NK; ++k) {
                    acc[i][2 * k] += xra[jj] * w[k][jj];
                    acc[i][2 * k + 1] += xia[jj] * w[k][jj];
                }
        }
    }

#pragma unroll
    for (int i = 0; i < 8; ++i) {
        __half2* dst = XWh + (size_t)(rowbase + rg * 8 + i) * (NK * 64);
#pragma unroll
        for (int k = 0; k < NK; ++k)
            dst[k * 64 + col] = __floats2half2_rn(acc[i][2 * k], acc[i][2 * k + 1]);
    }
}

__global__ __launch_bounds__(256) void row_kernel(const int* __restrict__ rowst,
                                                  const float* __restrict__ payload,
                                                  const __half2* __restrict__ XWh,
                                                  const float* __restrict__ bias,
                                                  float* __restrict__ out) {
    const int r = blockIdx.x * 4 + (threadIdx.x >> 6);
    const int lane = threadIdx.x & 63;
    if (r >= N_NODES) return;
    const int start = rowst[r];
    const int end = rowst[r + 1];
    const float b = bias[lane];
    float accR = 0.0f, accI = 0.0f;
#pragma unroll 2
    for (int p = start; p < end; ++p) {
        f32x4 q0 = __builtin_nontemporal_load((const f32x4*)(payload + (size_t)p * 8));
        f32x4 q1 = __builtin_nontemporal_load((const f32x4*)(payload + (size_t)p * 8 + 4));
        const int col = __float_as_int(q0.x);
        const __half2* xw = XWh + (size_t)col * 192;
        float2 v0 = __half22float2(xw[lane]);
        float2 v1 = __half22float2(xw[64 + lane]);
        float2 v2 = __half22float2(xw[128 + lane]);
        accR += q0.z * v0.x - q0.w * v0.y;
        accI += q0.w * v0.x + q0.z * v0.y;
        accR += q1.x * v1.x - q1.y * v1.y;
        accI += q1.y * v1.x + q1.x * v1.y;
        accR += q1.z * v2.x - q1.w * v2.y;
        accI += q1.w * v2.x + q1.z * v2.y;
    }
    __builtin_nontemporal_store(accR + b, &out[(size_t)r * 64 + lane]);
    __builtin_nontemporal_store(accI + b, &out[(size_t)(N_NODES + r) * 64 + lane]);
}

template <int NK>
__global__ __launch_bounds__(256) void edge_kernel(const int* __restrict__ rows,
                                                   const int* __restrict__ cols,
                                                   const float* __restrict__ Lr,
                                                   const float* __restrict__ Li,
                                                   const __half2* __restrict__ XWh,
                                                   float* __restrict__ out) {
    const int gid = blockIdx.x * 256 + threadIdx.x;
    const int e = gid >> 6;
    const int lane = gid & 63;
    if (e >= E_EDGES) return;

    const int row = rows[e];
    const int colN = cols[e];
    const __half2* xw = XWh + (size_t)colN * (NK * 64);

    float rc = 0.0f, ic = 0.0f;
#pragma unroll
    for (int k = 0; k < NK; ++k) {
        const float lr = Lr[(size_t)k * E_EDGES + e];
        const float li = Li[(size_t)k * E_EDGES + e];
        float2 v = __half22float2(xw[k * 64 + lane]);
        rc += lr * v.x - li * v.y;
        ic += li * v.x + lr * v.y;
    }
    unsafeAtomicAdd(out + (size_t)row * 64 + lane, rc);
    unsafeAtomicAdd(out + ((size_t)N_NODES + row) * 64 + lane, ic);
}

extern "C" void kernel_launch(void* const* d_in, const int* in_sizes, int n_in,
                              void* d_out, int out_size, void* d_ws, size_t ws_size,
                              hipStream_t stream) {
    const float* Xr = (const float*)d_in[0];
    const float* Xi = (const float*)d_in[1];
    const int* ei = (const int*)d_in[2];
    const float* Lr = (const float*)d_in[3];
    const float* Li = (const float*)d_in[4];
    const float* W = (const float*)d_in[5];
    const float* bias = (const float*)d_in[6];
    float* out = (float*)d_out;

    const int* rows = ei;
    const int* cols = ei + E_EDGES;

    char* wsb = (char*)d_ws;
    const int e_grid = E_EDGES / 256;                             // 6250
    const int edge_grid = (int)((size_t)E_EDGES * 64 / 256);      // 400000
    const int gemm_grid = N_NODES / 32;                           // 3125

    // New-path ws layout
    __half2* Xh = (__half2*)wsb;                                  //  25,600,000 B
    __half2* Y = (__half2*)(wsb + 25600000);                      //  76,800,000 B
    float* payload = (float*)(wsb + 102400000);                   //  51,200,000 B
    int* counts = (int*)(wsb + 153600000);                        //     400,384 B
    int* rowst = (int*)(wsb + 154000384);                         //     400,384 B
    int* cursor = (int*)(wsb + 154400768);                        //     400,384 B
    int* btot = (int*)(wsb + 154801152);                          //       2,048 B
    const size_t need_new = 154803200;

    if (ws_size >= need_new) {
        xh_kernel<<<6250, 256, 0, stream>>>(Xr, Xi, Xh);
        zero_counts_kernel<<<NBLK, 256, 0, stream>>>(counts);
        hist_kernel<<<e_grid, 256, 0, stream>>>(rows, counts);
        scan_a_kernel<<<NBLK, 256, 0, stream>>>(counts, rowst, btot);
        scan_b_kernel<<<1, 512, 0, stream>>>(btot);
        scan_c_kernel<<<NBLK, 256, 0, stream>>>(btot, rowst, cursor);
        scatter_kernel<<<e_grid, 256, 0, stream>>>(rows, cols, Lr, Li, cursor,
                                                   (float4*)payload);
        row2_kernel<<<(N_NODES + 3) / 4, 256, 0, stream>>>(rowst, payload, Xh, Y);
        yw_kernel<<<gemm_grid, 256, 0, stream>>>(Y, W, bias, out);
        return;
    }

    // Round-4 fallback ws layout
    __half2* XWh = (__half2*)wsb;                                 //  76,800,000 B
    float* payload2 = (float*)(wsb + 76800000);                   //  51,200,000 B
    int* counts2 = (int*)(wsb + 128000000);
    int* rowst2 = (int*)(wsb + 128400384);
    int* cursor2 = (int*)(wsb + 128800768);
    int* btot2 = (int*)(wsb + 129201152);
    const size_t need_full = 129203200;
    const size_t need_onepass = 76800000;

    if (ws_size >= need_full) {
        zero_counts_kernel<<<NBLK, 256, 0, stream>>>(counts2);
        hist_kernel<<<e_grid, 256, 0, stream>>>(rows, counts2);
        scan_a_kernel<<<NBLK, 256, 0, stream>>>(counts2, rowst2, btot2);
        scan_b_kernel<<<1, 512, 0, stream>>>(btot2);
        scan_c_kernel<<<NBLK, 256, 0, stream>>>(btot2, rowst2, cursor2);
        scatter_kernel<<<e_grid, 256, 0, stream>>>(rows, cols, Lr, Li, cursor2,
                                                   (float4*)payload2);
        xw_kernel<3><<<gemm_grid, 256, 0, stream>>>(Xr, Xi, W, XWh);
        row_kernel<<<(N_NODES + 3) / 4, 256, 0, stream>>>(rowst2, payload2, XWh, bias, out);
    } else if (ws_size >= need_onepass) {
        init_out_kernel<<<2 * N_NODES * CH / 256, 256, 0, stream>>>(bias, out);
        xw_kernel<3><<<gemm_grid, 256, 0, stream>>>(Xr, Xi, W, XWh);
        edge_kernel<3><<<edge_grid, 256, 0, stream>>>(rows, cols, Lr, Li, XWh, out);
    } else {
        init_out_kernel<<<2 * N_NODES * CH / 256, 256, 0, stream>>>(bias, out);
        for (int k = 0; k < 3; ++k) {
            xw_kernel<1><<<gemm_grid, 256, 0, stream>>>(Xr, Xi, W + (size_t)k * 4096, XWh);
            edge_kernel<1><<<edge_grid, 256, 0, stream>>>(rows, cols,
                                                          Lr + (size_t)k * E_EDGES,
                                                          Li + (size_t)k * E_EDGES, XWh, out);
        }
    }
}